// Round 13
// baseline (75.237 us; speedup 1.0000x reference)
//
#include <hip/hip_runtime.h>
#include <math.h>

#define NB 16      // batch
#define NC 80      // classes
#define HH 128
#define WW 128
#define HW (HH*WW)
#define HW4 (HW/4)
#define NPIX (NB*HH*WW)   // 262144
#define NM 32      // boxes per batch
#define IMG 512.0f
#define NW 8               // waves per block = class groups
#define NCL (NC/NW)        // 10 classes per wave
#define MAIN_BLOCKS (NB*64)  // 1024 blocks, 2 rows each

// output layout (float offsets)
#define OFF_VALUES 0
#define OFF_IDXS   262144
#define OFF_BBOX   524288
#define OFF_KEEP   1572864
#define OFF_PFL    1835008
#define OFF_SZL    1835009
#define OFF_OSL    1835010
#define OFF_GTHM   1835011
// R7/R8: nt stores + unroll => partial-line streaming => 4x write amp (nt-specific; cached merges in L2).
// R12: duration invariant under instr-count/traffic/store-flavor => latency-bound on the
//      10-iter class loop (1-deep prefetch < contended load latency).
// R13: preload ALL 10 classes upfront (20 float4 in flight, ~80 VGPR) + static full unroll;
//      trade occupancy (8->4 waves/SIMD) for 10-deep MLP. Cached stores only.

// ws layout (bytes)
#define WS_BPS   0          // 512*16 = 8192 (float4 box params, class-sorted per batch)
#define WS_CSRS  8192       // 16*81*4 = 5184 -> ends 13376
#define WS_FPART 13376      // 1024*4 = 4096 -> ends 17472

typedef float vfloat4 __attribute__((ext_vector_type(4)));

__device__ __forceinline__ float smooth_l1(float p, float g) {
    float d = fabsf(p - g);
    return (d < 1.0f) ? 0.5f * d * d : d - 0.5f;
}
__device__ __forceinline__ float fmax3(float a, float b, float c) {
    return fmaxf(fmaxf(a, b), c);
}

// ---------------- kernel 1: box params + per-batch class CSR (sorted scatter) ----------------
__global__ void setup_kernel(const float* __restrict__ gtb, const int* __restrict__ gtc,
                             float4* __restrict__ bps, int* __restrict__ csr_start) {
    __shared__ float4 s_bp[NB * NM];
    __shared__ int    s_cls[NB * NM];
    __shared__ int    s_pos[NB][NC];
    int t = threadIdx.x;
    {
        const float* g = gtb + t * 4;
        float x1 = g[0], y1 = g[1], x2 = g[2], y2 = g[3];
        float cx = (x1 + x2) * 0.5f, cy = (y1 + y2) * 0.5f;
        float c0 = floorf(cx * 0.25f);
        float c1 = floorf(cy * 0.25f);
        float w = x2 - x1, h = y2 - y1;
        float sigma = fmaxf(w, h) * 0.25f;     // sizes.max(-1)/DS
        float4 p;
        p.x = c0; p.y = c1;
        p.z = 1.0f / (2.0f * sigma);
        p.w = 0.0f;
        s_bp[t] = p;
        s_cls[t] = gtc[t];
    }
    __syncthreads();
    for (int e = t; e < NB * (NC + 1); e += 512) {
        int b = e / (NC + 1), c = e - b * (NC + 1);
        int cnt = 0;
        #pragma unroll
        for (int m = 0; m < NM; ++m) cnt += (s_cls[b * NM + m] < c) ? 1 : 0;
        csr_start[e] = cnt;
        if (c < NC) s_pos[b][c] = cnt;
    }
    __syncthreads();
    {
        int b = t >> 5;
        int c = s_cls[t];
        int slot = atomicAdd(&s_pos[b][c], 1);
        bps[b * NM + slot] = s_bp[t];
    }
}

// ---------------- kernel 2: one-stop NMS + gt_hm + focal + argmax + bbox ----------------
// Block = 512 threads = 8 waves; tile = 2 rows x 128 cols; wave = one 10-class group;
// 4 px/lane. ALL 10 classes preloaded (2 float4 each) -> 10-deep MLP; static unroll.
__launch_bounds__(512)
__global__ void main_kernel(const float* __restrict__ hm,
                            const float* __restrict__ sz,
                            const float* __restrict__ osr,
                            const float4* __restrict__ bps,
                            const int* __restrict__ csr_start,
                            float* __restrict__ fpart,
                            float* __restrict__ out) {
    int blk = blockIdx.x;
    int b = blk >> 6;
    int i0 = (blk & 63) << 1;        // 2 rows per tile
    int tid = threadIdx.x;
    int wid = tid >> 6;              // wave id = class group
    int lane = tid & 63;
    int lane31 = lane & 31;
    int r = lane >> 5;               // 0/1: row within tile
    int i = i0 + r;
    int jb = lane31 << 2;            // col base
    int c0 = wid * NCL;

    __shared__ int    s_start[NC + 1];
    __shared__ float4 s_box[NM];
    __shared__ float  s_val[NW][256];
    __shared__ unsigned char s_cls[NW][256];
    __shared__ float  s_red[NW];

    for (int k = tid; k < NC + 1; k += 512) s_start[k] = csr_start[b * (NC + 1) + k];
    if (tid < NM) s_box[tid] = bps[b * NM + tid];
    __syncthreads();

    const float fi = (float)i, fjb = (float)jb;
    // halo row: r=0 -> row above tile (clamped), r=1 -> row below tile (clamped).
    // middle rows (i0, i0+1) are exchanged between half-waves via shfl_xor(.,32).
    int hrow = r ? ((i < HH - 1) ? i + 1 : HH - 1) : ((i > 0) ? i - 1 : 0);
    size_t base = ((size_t)b * NC + c0) * HW;

    const float4* pC = (const float4*)(hm + base + i    * WW + jb);
    const float4* pH = (const float4*)(hm + base + hrow * WW + jb);
    float* gp = out + OFF_GTHM + base + i * WW + jb;

    bool clampL = (lane31 == 0);
    bool clampR = (lane31 == 31);
    int srcG = (lane & 32) | ((lane31 + 1) & 31);   // lane holding next col-quad's gv[0] (same row)

    float bestv[4] = {-1.f, -1.f, -1.f, -1.f};
    int   bestc[4] = {0, 0, 0, 0};     // local class 0..9
    float facc = 0.0f;

    // ---- preload ALL classes: 20 loads in flight, consumed in order ----
    float4 C[NCL], H[NCL];
    #pragma unroll
    for (int cc = 0; cc < NCL; ++cc) {
        C[cc] = pC[(size_t)cc * HW4];
        H[cc] = pH[(size_t)cc * HW4];
    }

    #pragma unroll
    for (int cc = 0; cc < NCL; ++cc) {
        float4 cC = C[cc], cH = H[cc];
        float* gpc = gp + (size_t)cc * HW;
        int c = c0 + cc;
        int s0 = s_start[c], s1 = s_start[c + 1];

        // ---- 3x3 NMS: vertical max via halo + cross-half shuffle, then horizontal ----
        float h[4] = {cC.x, cC.y, cC.z, cC.w};
        float o0 = __shfl_xor(cC.x, 32);
        float o1 = __shfl_xor(cC.y, 32);
        float o2 = __shfl_xor(cC.z, 32);
        float o3 = __shfl_xor(cC.w, 32);
        float vm[4];
        vm[0] = fmax3(h[0], cH.x, o0);
        vm[1] = fmax3(h[1], cH.y, o1);
        vm[2] = fmax3(h[2], cH.z, o2);
        vm[3] = fmax3(h[3], cH.w, o3);
        float left  = __shfl_up(vm[3], 1);
        float right = __shfl_down(vm[0], 1);
        if (clampL) left  = vm[0];
        if (clampR) right = vm[3];
        float mx[4];
        mx[0] = fmax3(left,  vm[0], vm[1]);
        mx[1] = fmax3(vm[0], vm[1], vm[2]);
        mx[2] = fmax3(vm[1], vm[2], vm[3]);
        mx[3] = fmax3(vm[2], vm[3], right);
        #pragma unroll
        for (int k = 0; k < 4; ++k) {
            float p = (h[k] >= mx[k]) ? h[k] : 0.0f;
            if (p > bestv[k]) { bestv[k] = p; bestc[k] = cc; }
        }

        // ---- gt_hm + focal: wave-uniform fast path for empty classes (~2/3) ----
        float gv[4] = {0.f, 0.f, 0.f, 0.f};
        if (s0 != s1) {
            for (int kk = s0; kk < s1; ++kk) {
                float4 bx = s_box[kk];
                float d0 = fi - bx.x;
                float nis = -bx.z;
                float dj = fjb - bx.y;
                float e = d0 * d0;
                #pragma unroll
                for (int k = 0; k < 4; ++k) {
                    float d1 = dj + (float)k;
                    gv[k] = fmaxf(gv[k], __expf((e + d1 * d1) * nis));
                }
            }
            #pragma unroll
            for (int k = 0; k < 4; ++k) {
                float hk = h[k], ohk = 1.0f - hk;
                float gk = gv[k], omk = 1.0f - gk;
                float om2 = omk * omk, g2 = gk * gk;
                facc += (om2 * om2) * hk * hk * __logf(ohk)
                      + (g2 * g2) * ohk * ohk * __logf(hk);
            }
        } else {
            // g = 0 exactly: focal reduces to h^2 * log(1-h)
            #pragma unroll
            for (int k = 0; k < 4; ++k) {
                float hk = h[k];
                facc += hk * hk * __logf(1.0f - hk);
            }
        }

        // ---- coalesced cached store: lane l covers cols 4l+1..4l+4 (16B-aligned) ----
        float g4th = __shfl(gv[0], srcG);
        if (lane31 != 31) {
            vfloat4 sv = {gv[1], gv[2], gv[3], g4th};
            *(vfloat4*)(gpc + 1) = sv;
        } else {
            gpc[1] = gv[1];        // col 125
            gpc[2] = gv[2];        // col 126
            gpc[3] = gv[3];        // col 127
            gpc[-124] = g4th;      // col 0 (lane 0's gv[0])
        }
    }

    // publish per-group results to LDS
    int pl = r * 128 + jb;           // 0..255, multiple of 4
    float4 bv4 = {bestv[0], bestv[1], bestv[2], bestv[3]};
    *(float4*)&s_val[wid][pl] = bv4;
    unsigned int cpk = (unsigned)bestc[0] | ((unsigned)bestc[1] << 8) |
                       ((unsigned)bestc[2] << 16) | ((unsigned)bestc[3] << 24);
    *(unsigned int*)&s_cls[wid][pl] = cpk;

    // focal wave reduction
    #pragma unroll
    for (int off = 32; off > 0; off >>= 1) facc += __shfl_down(facc, off);
    if (lane == 0) s_red[wid] = facc;
    __syncthreads();

    if (tid < 256) {
        float bv = -1.0f; int bi = 0;
        #pragma unroll
        for (int g2 = 0; g2 < NW; ++g2) {
            float v = s_val[g2][tid];
            if (v > bv) { bv = v; bi = g2 * NCL + (int)s_cls[g2][tid]; }  // strict >: smallest class wins ties
        }
        int rr  = tid >> 7;          // 0/1
        int col = tid & 127;
        int ij  = (i0 + rr) * WW + col;
        int pix = b * HW + ij;
        out[OFF_VALUES + pix] = bv;
        out[OFF_IDXS + pix]   = (float)bi;
        out[OFF_KEEP + pix]   = (bv > 0.0f) ? 1.0f : 0.0f;

        const float* szb = sz  + (size_t)b * 2 * HW;
        const float* osb = osr + (size_t)b * 2 * HW;
        float s0v = szb[ij], s1v = szb[HW + ij];
        float o0 = osb[ij],  o1 = osb[HW + ij];
        float cx = (float)(i0 + rr) * 4.0f + o0;
        float cy = (float)col * 4.0f + o1;
        float4 bb;
        bb.x = fminf(fmaxf(cx - s0v * 0.5f, 0.0f), IMG);
        bb.y = fminf(fmaxf(cy - s1v * 0.5f, 0.0f), IMG);
        bb.z = fminf(fmaxf(cx + s0v * 0.5f, 0.0f), IMG);
        bb.w = fminf(fmaxf(cy + s1v * 0.5f, 0.0f), IMG);
        reinterpret_cast<float4*>(out + OFF_BBOX)[pix] = bb;
    }
    if (tid == 0) {
        float t = 0.0f;
        #pragma unroll
        for (int g2 = 0; g2 < NW; ++g2) t += s_red[g2];
        fpart[blk] = t;
    }
}

// ---------------- kernel 3: size/offset losses + focal partial reduction ----------------
__global__ void loss_kernel(const float* __restrict__ gtb, const float* __restrict__ sz,
                            const float* __restrict__ osr, const float* __restrict__ fpart,
                            float* __restrict__ out) {
    int t = threadIdx.x;
    int b = t >> 5, m = t & 31;
    __shared__ int s_ci[NB * NM];
    const float* g = gtb + t * 4;
    float x1 = g[0], y1 = g[1], x2 = g[2], y2 = g[3];
    float cx = (x1 + x2) * 0.5f, cy = (y1 + y2) * 0.5f;
    float c0f = floorf(cx * 0.25f), c1f = floorf(cy * 0.25f);
    int ci0 = (int)c0f, ci1 = (int)c1f;
    s_ci[t] = ci0 * WW + ci1;
    __syncthreads();

    bool winner = true;
    int mycell = s_ci[t];
    for (int m2 = m + 1; m2 < NM; ++m2)
        if (s_ci[b * NM + m2] == mycell) { winner = false; break; }

    float nloc = 0.0f, szs = 0.0f, oss = 0.0f;
    if (winner) {
        nloc = 1.0f;
        float w = x2 - x1, h = y2 - y1;
        float offx = cx * 0.25f - c0f, offy = cy * 0.25f - c1f;
        size_t pb = (size_t)b * 2 * HW + (size_t)ci0 * WW + ci1;
        float ps0 = sz[pb], ps1 = sz[pb + HW];
        float po0 = osr[pb], po1 = osr[pb + HW];
        szs = smooth_l1(ps0, w) + smooth_l1(ps1, h);
        oss = smooth_l1(po0, offx) + smooth_l1(po1, offy);
    }

    // focal partials: 1024 entries, 2 per thread
    float fsum = fpart[t] + fpart[t + 512];

    #pragma unroll
    for (int off = 32; off > 0; off >>= 1) {
        nloc += __shfl_down(nloc, off);
        szs  += __shfl_down(szs, off);
        oss  += __shfl_down(oss, off);
        fsum += __shfl_down(fsum, off);
    }
    __shared__ float red[8][4];
    int wid = t >> 6;
    if ((t & 63) == 0) { red[wid][0] = nloc; red[wid][1] = szs; red[wid][2] = oss; red[wid][3] = fsum; }
    __syncthreads();
    if (t == 0) {
        float n = 0.0f, ss = 0.0f, os_ = 0.0f, ft = 0.0f;
        for (int w2 = 0; w2 < 8; ++w2) { n += red[w2][0]; ss += red[w2][1]; os_ += red[w2][2]; ft += red[w2][3]; }
        out[OFF_SZL] = ss / (2.0f * n) / n;
        out[OFF_OSL] = os_ / (2.0f * n) / n;
        out[OFF_PFL] = -ft;
    }
}

extern "C" void kernel_launch(void* const* d_in, const int* in_sizes, int n_in,
                              void* d_out, int out_size, void* d_ws, size_t ws_size,
                              hipStream_t stream) {
    const float* hm  = (const float*)d_in[0];
    const float* sz  = (const float*)d_in[1];
    const float* osr = (const float*)d_in[2];
    const float* gtb = (const float*)d_in[3];
    const int*   gtc = (const int*)d_in[4];
    float* out = (float*)d_out;

    float4* bps    = (float4*)((char*)d_ws + WS_BPS);
    int* csr_start = (int*)((char*)d_ws + WS_CSRS);
    float* fpart   = (float*)((char*)d_ws + WS_FPART);

    setup_kernel<<<1, 512, 0, stream>>>(gtb, gtc, bps, csr_start);
    main_kernel<<<MAIN_BLOCKS, 512, 0, stream>>>(hm, sz, osr, bps, csr_start, fpart, out);
    loss_kernel<<<1, 512, 0, stream>>>(gtb, sz, osr, fpart, out);
}

// Round 14
// 55.755 us; speedup vs baseline: 1.3494x; 1.3494x over previous
//
#include <hip/hip_runtime.h>
#include <math.h>

#define NB 16      // batch
#define NC 80      // classes
#define HH 128
#define WW 128
#define HW (HH*WW)
#define HW4 (HW/4)
#define NPIX (NB*HH*WW)   // 262144
#define NM 32      // boxes per batch
#define IMG 512.0f
#define NW 8               // waves per block = class groups
#define NCL (NC/NW)        // 10 classes per wave
#define MAIN_BLOCKS (NB*64)  // 1024 blocks, 2 rows each

// output layout (float offsets)
#define OFF_VALUES 0
#define OFF_IDXS   262144
#define OFF_BBOX   524288
#define OFF_KEEP   1572864
#define OFF_PFL    1835008
#define OFF_SZL    1835009
#define OFF_OSL    1835010
#define OFF_GTHM   1835011
// R7/R8: nt stores + unroll => partial-line streaming => 4x write amp. Loop stays ROLLED.
// R12: best config (55.5 us main). R13: 10-deep preload => VGPR 80, occupancy 23%, 73 us. REVERTED.
// Plateau evidence: duration invariant under instr count (+-40%), store flavor, traffic, residency;
// structural latency floor of the fused single-pass design.

// ws layout (bytes)
#define WS_BPS   0          // 512*16 = 8192 (float4 box params, class-sorted per batch)
#define WS_CSRS  8192       // 16*81*4 = 5184 -> ends 13376
#define WS_FPART 13376      // 1024*4 = 4096 -> ends 17472

typedef float vfloat4 __attribute__((ext_vector_type(4)));

__device__ __forceinline__ float smooth_l1(float p, float g) {
    float d = fabsf(p - g);
    return (d < 1.0f) ? 0.5f * d * d : d - 0.5f;
}
__device__ __forceinline__ float fmax3(float a, float b, float c) {
    return fmaxf(fmaxf(a, b), c);
}

// ---------------- kernel 1: box params + per-batch class CSR (sorted scatter) ----------------
__global__ void setup_kernel(const float* __restrict__ gtb, const int* __restrict__ gtc,
                             float4* __restrict__ bps, int* __restrict__ csr_start) {
    __shared__ float4 s_bp[NB * NM];
    __shared__ int    s_cls[NB * NM];
    __shared__ int    s_pos[NB][NC];
    int t = threadIdx.x;
    {
        const float* g = gtb + t * 4;
        float x1 = g[0], y1 = g[1], x2 = g[2], y2 = g[3];
        float cx = (x1 + x2) * 0.5f, cy = (y1 + y2) * 0.5f;
        float c0 = floorf(cx * 0.25f);
        float c1 = floorf(cy * 0.25f);
        float w = x2 - x1, h = y2 - y1;
        float sigma = fmaxf(w, h) * 0.25f;     // sizes.max(-1)/DS
        float4 p;
        p.x = c0; p.y = c1;
        p.z = 1.0f / (2.0f * sigma);
        p.w = 0.0f;
        s_bp[t] = p;
        s_cls[t] = gtc[t];
    }
    __syncthreads();
    for (int e = t; e < NB * (NC + 1); e += 512) {
        int b = e / (NC + 1), c = e - b * (NC + 1);
        int cnt = 0;
        #pragma unroll
        for (int m = 0; m < NM; ++m) cnt += (s_cls[b * NM + m] < c) ? 1 : 0;
        csr_start[e] = cnt;
        if (c < NC) s_pos[b][c] = cnt;
    }
    __syncthreads();
    {
        int b = t >> 5;
        int c = s_cls[t];
        int slot = atomicAdd(&s_pos[b][c], 1);
        bps[b * NM + slot] = s_bp[t];
    }
}

// ---------------- kernel 2: one-stop NMS + gt_hm + focal + argmax + bbox ----------------
// Block = 512 threads = 8 waves; tile = 2 rows x 128 cols; wave = one 10-class group;
// 4 px/lane. ROLLED loop, 1-deep prefetch, 2 loads/quad (own row + halo row; middle
// rows shared across half-waves via shfl_xor 32), single coalesced cached store.
__launch_bounds__(512, 8)
__global__ void main_kernel(const float* __restrict__ hm,
                            const float* __restrict__ sz,
                            const float* __restrict__ osr,
                            const float4* __restrict__ bps,
                            const int* __restrict__ csr_start,
                            float* __restrict__ fpart,
                            float* __restrict__ out) {
    int blk = blockIdx.x;
    int b = blk >> 6;
    int i0 = (blk & 63) << 1;        // 2 rows per tile
    int tid = threadIdx.x;
    int wid = tid >> 6;              // wave id = class group
    int lane = tid & 63;
    int lane31 = lane & 31;
    int r = lane >> 5;               // 0/1: row within tile
    int i = i0 + r;
    int jb = lane31 << 2;            // col base
    int c0 = wid * NCL;

    __shared__ int    s_start[NC + 1];
    __shared__ float4 s_box[NM];
    __shared__ float  s_val[NW][256];
    __shared__ unsigned char s_cls[NW][256];
    __shared__ float  s_red[NW];

    for (int k = tid; k < NC + 1; k += 512) s_start[k] = csr_start[b * (NC + 1) + k];
    if (tid < NM) s_box[tid] = bps[b * NM + tid];
    __syncthreads();

    const float fi = (float)i, fjb = (float)jb;
    // halo row: r=0 -> row above tile (clamped), r=1 -> row below tile (clamped).
    // middle rows (i0, i0+1) are exchanged between half-waves via shfl_xor(.,32).
    int hrow = r ? ((i < HH - 1) ? i + 1 : HH - 1) : ((i > 0) ? i - 1 : 0);
    size_t base = ((size_t)b * NC + c0) * HW;

    const float4* pC = (const float4*)(hm + base + i    * WW + jb);
    const float4* pH = (const float4*)(hm + base + hrow * WW + jb);
    float* gp = out + OFF_GTHM + base + i * WW + jb;

    bool clampL = (lane31 == 0);
    bool clampR = (lane31 == 31);
    int srcG = (lane & 32) | ((lane31 + 1) & 31);   // lane holding next col-quad's gv[0] (same row)

    float bestv[4] = {-1.f, -1.f, -1.f, -1.f};
    int   bestc[4] = {0, 0, 0, 0};     // local class 0..9
    float facc = 0.0f;

    auto process = [&](float4 cC, float4 cH, int cc, float* gpc) {
        int c = c0 + cc;
        int s0 = s_start[c], s1 = s_start[c + 1];

        // ---- 3x3 NMS: vertical max via halo + cross-half shuffle, then horizontal ----
        float h[4] = {cC.x, cC.y, cC.z, cC.w};
        float o0 = __shfl_xor(cC.x, 32);
        float o1 = __shfl_xor(cC.y, 32);
        float o2 = __shfl_xor(cC.z, 32);
        float o3 = __shfl_xor(cC.w, 32);
        float vm[4];
        vm[0] = fmax3(h[0], cH.x, o0);
        vm[1] = fmax3(h[1], cH.y, o1);
        vm[2] = fmax3(h[2], cH.z, o2);
        vm[3] = fmax3(h[3], cH.w, o3);
        float left  = __shfl_up(vm[3], 1);
        float right = __shfl_down(vm[0], 1);
        if (clampL) left  = vm[0];
        if (clampR) right = vm[3];
        float mx[4];
        mx[0] = fmax3(left,  vm[0], vm[1]);
        mx[1] = fmax3(vm[0], vm[1], vm[2]);
        mx[2] = fmax3(vm[1], vm[2], vm[3]);
        mx[3] = fmax3(vm[2], vm[3], right);
        #pragma unroll
        for (int k = 0; k < 4; ++k) {
            float p = (h[k] >= mx[k]) ? h[k] : 0.0f;
            if (p > bestv[k]) { bestv[k] = p; bestc[k] = cc; }
        }

        // ---- gt_hm + focal: wave-uniform fast path for empty classes (~2/3) ----
        float gv[4] = {0.f, 0.f, 0.f, 0.f};
        if (s0 != s1) {
            for (int kk = s0; kk < s1; ++kk) {
                float4 bx = s_box[kk];
                float d0 = fi - bx.x;
                float nis = -bx.z;
                float dj = fjb - bx.y;
                float e = d0 * d0;
                #pragma unroll
                for (int k = 0; k < 4; ++k) {
                    float d1 = dj + (float)k;
                    gv[k] = fmaxf(gv[k], __expf((e + d1 * d1) * nis));
                }
            }
            #pragma unroll
            for (int k = 0; k < 4; ++k) {
                float hk = h[k], ohk = 1.0f - hk;
                float gk = gv[k], omk = 1.0f - gk;
                float om2 = omk * omk, g2 = gk * gk;
                facc += (om2 * om2) * hk * hk * __logf(ohk)
                      + (g2 * g2) * ohk * ohk * __logf(hk);
            }
        } else {
            // g = 0 exactly: focal reduces to h^2 * log(1-h)
            #pragma unroll
            for (int k = 0; k < 4; ++k) {
                float hk = h[k];
                facc += hk * hk * __logf(1.0f - hk);
            }
        }

        // ---- coalesced cached store: lane l covers cols 4l+1..4l+4 (16B-aligned) ----
        float g4th = __shfl(gv[0], srcG);
        if (lane31 != 31) {
            vfloat4 sv = {gv[1], gv[2], gv[3], g4th};
            *(vfloat4*)(gpc + 1) = sv;
        } else {
            gpc[1] = gv[1];        // col 125
            gpc[2] = gv[2];        // col 126
            gpc[3] = gv[3];        // col 127
            gpc[-124] = g4th;      // col 0 (lane 0's gv[0])
        }
    };

    float4 cC = *pC, cH = *pH;
    for (int cc = 0; cc < NCL - 1; ++cc) {        // rolled: store groups stay contiguous
        float4 nC = pC[HW4], nH = pH[HW4];        // 1-deep prefetch
        process(cC, cH, cc, gp);
        pC += HW4; pH += HW4; gp += HW;
        cC = nC; cH = nH;
    }
    process(cC, cH, NCL - 1, gp);

    // publish per-group results to LDS
    int pl = r * 128 + jb;           // 0..255, multiple of 4
    float4 bv4 = {bestv[0], bestv[1], bestv[2], bestv[3]};
    *(float4*)&s_val[wid][pl] = bv4;
    unsigned int cpk = (unsigned)bestc[0] | ((unsigned)bestc[1] << 8) |
                       ((unsigned)bestc[2] << 16) | ((unsigned)bestc[3] << 24);
    *(unsigned int*)&s_cls[wid][pl] = cpk;

    // focal wave reduction
    #pragma unroll
    for (int off = 32; off > 0; off >>= 1) facc += __shfl_down(facc, off);
    if (lane == 0) s_red[wid] = facc;
    __syncthreads();

    if (tid < 256) {
        float bv = -1.0f; int bi = 0;
        #pragma unroll
        for (int g2 = 0; g2 < NW; ++g2) {
            float v = s_val[g2][tid];
            if (v > bv) { bv = v; bi = g2 * NCL + (int)s_cls[g2][tid]; }  // strict >: smallest class wins ties
        }
        int rr  = tid >> 7;          // 0/1
        int col = tid & 127;
        int ij  = (i0 + rr) * WW + col;
        int pix = b * HW + ij;
        out[OFF_VALUES + pix] = bv;
        out[OFF_IDXS + pix]   = (float)bi;
        out[OFF_KEEP + pix]   = (bv > 0.0f) ? 1.0f : 0.0f;

        const float* szb = sz  + (size_t)b * 2 * HW;
        const float* osb = osr + (size_t)b * 2 * HW;
        float s0v = szb[ij], s1v = szb[HW + ij];
        float o0 = osb[ij],  o1 = osb[HW + ij];
        float cx = (float)(i0 + rr) * 4.0f + o0;
        float cy = (float)col * 4.0f + o1;
        float4 bb;
        bb.x = fminf(fmaxf(cx - s0v * 0.5f, 0.0f), IMG);
        bb.y = fminf(fmaxf(cy - s1v * 0.5f, 0.0f), IMG);
        bb.z = fminf(fmaxf(cx + s0v * 0.5f, 0.0f), IMG);
        bb.w = fminf(fmaxf(cy + s1v * 0.5f, 0.0f), IMG);
        reinterpret_cast<float4*>(out + OFF_BBOX)[pix] = bb;
    }
    if (tid == 0) {
        float t = 0.0f;
        #pragma unroll
        for (int g2 = 0; g2 < NW; ++g2) t += s_red[g2];
        fpart[blk] = t;
    }
}

// ---------------- kernel 3: size/offset losses + focal partial reduction ----------------
__global__ void loss_kernel(const float* __restrict__ gtb, const float* __restrict__ sz,
                            const float* __restrict__ osr, const float* __restrict__ fpart,
                            float* __restrict__ out) {
    int t = threadIdx.x;
    int b = t >> 5, m = t & 31;
    __shared__ int s_ci[NB * NM];
    const float* g = gtb + t * 4;
    float x1 = g[0], y1 = g[1], x2 = g[2], y2 = g[3];
    float cx = (x1 + x2) * 0.5f, cy = (y1 + y2) * 0.5f;
    float c0f = floorf(cx * 0.25f), c1f = floorf(cy * 0.25f);
    int ci0 = (int)c0f, ci1 = (int)c1f;
    s_ci[t] = ci0 * WW + ci1;
    __syncthreads();

    bool winner = true;
    int mycell = s_ci[t];
    for (int m2 = m + 1; m2 < NM; ++m2)
        if (s_ci[b * NM + m2] == mycell) { winner = false; break; }

    float nloc = 0.0f, szs = 0.0f, oss = 0.0f;
    if (winner) {
        nloc = 1.0f;
        float w = x2 - x1, h = y2 - y1;
        float offx = cx * 0.25f - c0f, offy = cy * 0.25f - c1f;
        size_t pb = (size_t)b * 2 * HW + (size_t)ci0 * WW + ci1;
        float ps0 = sz[pb], ps1 = sz[pb + HW];
        float po0 = osr[pb], po1 = osr[pb + HW];
        szs = smooth_l1(ps0, w) + smooth_l1(ps1, h);
        oss = smooth_l1(po0, offx) + smooth_l1(po1, offy);
    }

    // focal partials: 1024 entries, 2 per thread
    float fsum = fpart[t] + fpart[t + 512];

    #pragma unroll
    for (int off = 32; off > 0; off >>= 1) {
        nloc += __shfl_down(nloc, off);
        szs  += __shfl_down(szs, off);
        oss  += __shfl_down(oss, off);
        fsum += __shfl_down(fsum, off);
    }
    __shared__ float red[8][4];
    int wid = t >> 6;
    if ((t & 63) == 0) { red[wid][0] = nloc; red[wid][1] = szs; red[wid][2] = oss; red[wid][3] = fsum; }
    __syncthreads();
    if (t == 0) {
        float n = 0.0f, ss = 0.0f, os_ = 0.0f, ft = 0.0f;
        for (int w2 = 0; w2 < 8; ++w2) { n += red[w2][0]; ss += red[w2][1]; os_ += red[w2][2]; ft += red[w2][3]; }
        out[OFF_SZL] = ss / (2.0f * n) / n;
        out[OFF_OSL] = os_ / (2.0f * n) / n;
        out[OFF_PFL] = -ft;
    }
}

extern "C" void kernel_launch(void* const* d_in, const int* in_sizes, int n_in,
                              void* d_out, int out_size, void* d_ws, size_t ws_size,
                              hipStream_t stream) {
    const float* hm  = (const float*)d_in[0];
    const float* sz  = (const float*)d_in[1];
    const float* osr = (const float*)d_in[2];
    const float* gtb = (const float*)d_in[3];
    const int*   gtc = (const int*)d_in[4];
    float* out = (float*)d_out;

    float4* bps    = (float4*)((char*)d_ws + WS_BPS);
    int* csr_start = (int*)((char*)d_ws + WS_CSRS);
    float* fpart   = (float*)((char*)d_ws + WS_FPART);

    setup_kernel<<<1, 512, 0, stream>>>(gtb, gtc, bps, csr_start);
    main_kernel<<<MAIN_BLOCKS, 512, 0, stream>>>(hm, sz, osr, bps, csr_start, fpart, out);
    loss_kernel<<<1, 512, 0, stream>>>(gtb, sz, osr, fpart, out);
}